// Round 1
// baseline (254.000 us; speedup 1.0000x reference)
//
#include <hip/hip_runtime.h>

// Problem constants (from reference):
//   inputs  [B=64, H=512, W=512, C=3] float32
//   offsets [B=64, 2] float32
//   output  [B=64, 64, 64, C*DEPTH=9] float32, out[...,c*3+d]
#define OSZ 64
#define NB  64
#define IH  512
#define IW  512
#define NC  3
#define ND  3

// k x k mean of unit-spaced bilinear samples == separable (k+1)-tap filter
// with per-axis weights [1-f, 1, ..., 1, f] / k. OOB taps get weight 0
// (matches reference's per-gather zero masking).
template<int K>
__device__ __forceinline__ void glimpse_eval(const float* __restrict__ img,
                                             int b, int y, int x,
                                             float cy, float cx,
                                             float* __restrict__ out3) {
    // (float)(y*K) - halfspan is exact (half-integer); single rounding on +cy
    // matches reference's cy + (i - (hd-1)/2) bit-for-bit.
    const float halfspan = (float)(OSZ * K - 1) * 0.5f;
    float ybase = cy + ((float)(y * K) - halfspan);
    float xbase = cx + ((float)(x * K) - halfspan);
    float y0f = floorf(ybase), x0f = floorf(xbase);
    float fy = ybase - y0f, fx = xbase - x0f;
    int y0 = (int)y0f, x0 = (int)x0f;

    float wx[K + 1];
    wx[0] = 1.0f - fx;
#pragma unroll
    for (int s = 1; s < K; ++s) wx[s] = 1.0f;
    wx[K] = fx;
#pragma unroll
    for (int s = 0; s <= K; ++s) {
        int xi = x0 + s;
        if (xi < 0 || xi >= IW) wx[s] = 0.0f;
    }

    float a0 = 0.f, a1 = 0.f, a2 = 0.f;
#pragma unroll
    for (int r = 0; r <= K; ++r) {
        int yi = y0 + r;
        float wy = (r == 0) ? (1.0f - fy) : ((r == K) ? fy : 1.0f);
        if (yi < 0 || yi >= IH) continue;  // weight-zero row: skip entirely
        const float* rowp = img + ((size_t)b * IH + (size_t)yi) * (IW * NC);
        float r0 = 0.f, r1 = 0.f, r2 = 0.f;
#pragma unroll
        for (int s = 0; s <= K; ++s) {
            int xi = x0 + s;
            int xc = xi < 0 ? 0 : (xi >= IW ? IW - 1 : xi);  // safe addr; w=0 if OOB
            const float* p = rowp + xc * NC;
            float w = wx[s];
            r0 += w * p[0];
            r1 += w * p[1];
            r2 += w * p[2];
        }
        a0 += wy * r0; a1 += wy * r1; a2 += wy * r2;
    }
    const float inv = 1.0f / (float)(K * K);
    out3[0] = a0 * inv; out3[1] = a1 * inv; out3[2] = a2 * inv;
}

__global__ __launch_bounds__(256)
void SpatialGlimpse_kernel(const float* __restrict__ img,
                           const float* __restrict__ off,
                           float* __restrict__ out) {
    int idx = blockIdx.x * 256 + threadIdx.x;
    // idx = ((d*NB + b)*OSZ + y)*OSZ + x ; d is block-uniform (2^18 per depth)
    int x = idx & 63;
    int y = (idx >> 6) & 63;
    int b = (idx >> 12) & 63;
    int d = idx >> 18;

    float cy = (off[2 * b + 0] + 1.0f) * ((float)IH * 0.5f);
    float cx = (off[2 * b + 1] + 1.0f) * ((float)IW * 0.5f);

    float v[3];
    if (d == 0)      glimpse_eval<1>(img, b, y, x, cy, cx, v);
    else if (d == 1) glimpse_eval<2>(img, b, y, x, cy, cx, v);
    else             glimpse_eval<4>(img, b, y, x, cy, cx, v);

    size_t o = (((size_t)b * OSZ + y) * OSZ + x) * (NC * ND) + d;
    out[o]          = v[0];
    out[o + ND]     = v[1];
    out[o + 2 * ND] = v[2];
}

extern "C" void kernel_launch(void* const* d_in, const int* in_sizes, int n_in,
                              void* d_out, int out_size, void* d_ws, size_t ws_size,
                              hipStream_t stream) {
    const float* img = (const float*)d_in[0];
    const float* off = (const float*)d_in[1];
    float* out = (float*)d_out;

    const int total = ND * NB * OSZ * OSZ;       // 786432 threads
    const int block = 256;
    const int grid = total / block;              // 3072 blocks
    SpatialGlimpse_kernel<<<grid, block, 0, stream>>>(img, off, out);
}